// Round 4
// baseline (1054.010 us; speedup 1.0000x reference)
//
#include <hip/hip_runtime.h>
#include <math.h>

#define NUM_NODES 2000000
#define NUM_FLOPS 800000
#define NBX 168
#define NBY 480
#define NKE 64                      // 8 ck * 8 ce
#define NBINS (NBX * NBY)           // 80,640
#define S_INVSQRT2 0.7071067811865476f

// -------- workspace layout --------
// dem : float [NBINS * NKE] @ offset 0   (20.64 MB, < 20.97 MB proven cap)
// After ff_reduce, scale[t] is aliased into dem[t*64] (read-then-overwrite by
// the owning thread only). No other workspace needed.

// Branch-free erf, Abramowitz-Stegun 7.1.26 (max abs err 1.5e-7).
__device__ __forceinline__ float fast_erf(float x) {
    float ax = fabsf(x);
    float t = __builtin_amdgcn_rcpf(fmaf(0.3275911f, ax, 1.0f));
    float p = t * fmaf(t, fmaf(t, fmaf(t, fmaf(t, 1.061405429f, -1.453152027f),
                                       1.421413741f), -0.284496736f), 0.254829592f);
    float r = fmaf(-p, __expf(-ax * ax), 1.0f);
    return copysignf(r, x);
}

// R0-R3 established: per-CU LDS atomic units serialize at ~3.4 cyc/active-lane
// (20M lane-RMWs -> flat ~112 us core, invariant under all restructuring).
// This version routes the same 20M adds to the memory-side LLC atomic units
// via no-return device-scope global_atomic_add_f32, and deletes the whole
// record/bucket pipeline (no Rec12, no cnt, no LDS, 1 fused scatter kernel).
__global__ void __launch_bounds__(256)
ff_scatter(const float* __restrict__ pos,
           const float* __restrict__ nsx,
           const float* __restrict__ nsy,
           const int* __restrict__ fi,
           const int* __restrict__ cs,
           float* __restrict__ dem,
           float* __restrict__ out) {
    int f = blockIdx.x * 256 + threadIdx.x;        // grid is exactly 800,000 threads

    // fused: zero the output array (3 strided stores/thread)
    for (int g = f; g < NUM_NODES; g += NUM_FLOPS) out[g] = 0.f;

    int i = fi[f];
    float cx = pos[i] + 0.5f * nsx[i];
    float cy = pos[NUM_NODES + i] + 0.5f * nsy[i];
    int bx0 = (int)floorf(cx); bx0 = bx0 < 0 ? 0 : (bx0 > NBX - 1 ? NBX - 1 : bx0);
    int by0 = (int)floorf(cy); by0 = by0 < 0 ? 0 : (by0 > NBY - 1 ? NBY - 1 : by0);
    int2 cc = ((const int2*)cs)[f];
    int ke = cc.x * 8 + cc.y;

    float ex[6], ey[6];
#pragma unroll
    for (int t = 0; t < 6; ++t) {                  // 12 independent erfs
        ex[t] = fast_erf(((float)(bx0 - 2 + t) - cx) * S_INVSQRT2);
        ey[t] = fast_erf(((float)(by0 - 2 + t) - cy) * S_INVSQRT2);
    }
    float dyq[5];
#pragma unroll
    for (int j = 0; j < 5; ++j) dyq[j] = ey[j + 1] - ey[j];

    // dem contribution = 0.25 * dEx * dEy  (== reference 0.5dEx * 0.5dEy, INST_AREA=1)
#pragma unroll
    for (int ix = 0; ix < 5; ++ix) {
        int bx = bx0 - 2 + ix;
        if ((unsigned)bx < NBX) {
            float dxq = 0.25f * (ex[ix + 1] - ex[ix]);
            size_t rowbase = ((size_t)bx * NBY + (by0 - 2)) * NKE + ke;
#pragma unroll
            for (int iy = 0; iy < 5; ++iy) {
                int by = by0 - 2 + iy;
                if ((unsigned)by < NBY)
                    unsafeAtomicAdd(&dem[rowbase + (size_t)iy * NKE], dxq * dyq[iy]);
            }
        }
    }
}

// One thread per (x,y) bin: read its 64 ke-values (256B contiguous -> wave
// reads 16KB contiguous), quantize, write scale aliased into dem[t*64].
__global__ void __launch_bounds__(256)
ff_reduce(float* __restrict__ dem) {
    int t = blockIdx.x * 256 + threadIdx.x;
    if (t >= NBINS) return;
    const float4* p = (const float4*)(dem + (size_t)t * NKE);
    float tot = 0.f, halves = 0.f;
#pragma unroll
    for (int ck = 0; ck < 8; ++ck) {
        float q = 0.f;
#pragma unroll
        for (int h2 = 0; h2 < 2; ++h2) {
            float4 d = p[ck * 2 + h2];
            tot += d.x + d.y + d.z + d.w;
            q += ceilf(d.x * 0.25f) + ceilf(d.y * 0.25f) +
                 ceilf(d.z * 0.25f) + ceilf(d.w * 0.25f);
        }
        halves += ceilf(0.5f * q);
    }
    float slices = ceilf(0.5f * halves);
    dem[(size_t)t * NKE] = (tot > 0.f) ? (slices / fmaxf(tot, 1e-12f)) : 0.f;
}

__global__ void __launch_bounds__(256)
ff_gather(const float* __restrict__ pos,
          const float* __restrict__ nsx,
          const float* __restrict__ nsy,
          const int* __restrict__ fi,
          const float* __restrict__ dem,
          float* __restrict__ out) {
    int f = blockIdx.x * 256 + threadIdx.x;
    if (f >= NUM_FLOPS) return;
    int i = fi[f];
    float cx = pos[i] + 0.5f * nsx[i];
    float cy = pos[NUM_NODES + i] + 0.5f * nsy[i];
    int bx0 = (int)floorf(cx); bx0 = bx0 < 0 ? 0 : (bx0 > NBX - 1 ? NBX - 1 : bx0);
    int by0 = (int)floorf(cy); by0 = by0 < 0 ? 0 : (by0 > NBY - 1 ? NBY - 1 : by0);
    out[i] = dem[(size_t)(bx0 * NBY + by0) * NKE];   // scale aliased at ke=0 slot
}

extern "C" void kernel_launch(void* const* d_in, const int* in_sizes, int n_in,
                              void* d_out, int out_size, void* d_ws, size_t ws_size,
                              hipStream_t stream) {
    const float* pos = (const float*)d_in[0];
    const float* nsx = (const float*)d_in[1];
    const float* nsy = (const float*)d_in[2];
    const int*   fi  = (const int*)d_in[3];
    const int*   cs  = (const int*)d_in[4];
    float* out = (float*)d_out;
    float* dem = (float*)d_ws;                       // 20,643,840 B

    hipMemsetAsync(dem, 0, (size_t)NBINS * NKE * sizeof(float), stream);

    ff_scatter<<<NUM_FLOPS / 256, 256, 0, stream>>>(pos, nsx, nsy, fi, cs, dem, out);
    ff_reduce<<<(NBINS + 255) / 256, 256, 0, stream>>>(dem);
    ff_gather<<<NUM_FLOPS / 256, 256, 0, stream>>>(pos, nsx, nsy, fi, dem, out);
}

// Round 5
// 239.171 us; speedup vs baseline: 4.4069x; 4.4069x over previous
//
#include <hip/hip_runtime.h>
#include <math.h>

#define NUM_NODES 2000000
#define NUM_FLOPS 800000
#define NBX 168
#define NBY 480
#define NCK 8
#define NCE 8
#define NBINS (NBX * NBY)          // 80,640
#define YB_ROWS 20                 // y-bucket / tile granularity
#define NYB 24                     // y-buckets per column
#define NBUCK (NYB * NBX)          // 4,032 buckets
#define CAPB 416
#define W 4                        // columns owned per ff_main block
#define KSTRIDE 68                 // ke-dim stride (64 + 4 pad)
#define S_INVSQRT2 0.7071067811865476f
#define FILL_THREADS (784 * 1024)
#define PROBE_REPS 8               // make one-shot probes slower than ff_main -> visible in top-5

struct Rec12 { float cx, cy; int keby; };

// one-shot probe gate: module-scope device var survives across bench iterations
// within a process; ff_arm (launched last) sets it after iteration 0's probes.
__device__ int g_probe_armed = 0;

__device__ __forceinline__ float fast_erf(float x) {
    float ax = fabsf(x);
    float t = __builtin_amdgcn_rcpf(fmaf(0.3275911f, ax, 1.0f));
    float p = t * fmaf(t, fmaf(t, fmaf(t, fmaf(t, 1.061405429f, -1.453152027f),
                                       1.421413741f), -0.284496736f), 0.254829592f);
    float r = fmaf(-p, __expf(-ax * ax), 1.0f);
    return copysignf(r, x);
}

__device__ __forceinline__ void lds_fadd(float* p, float v) {
    unsafeAtomicAdd(p, v);
}

__global__ void __launch_bounds__(1024)
ff_fill(const float* __restrict__ pos,
        const float* __restrict__ nsx,
        const float* __restrict__ nsy,
        const int* __restrict__ fi,
        const int* __restrict__ cs,
        int* __restrict__ cnt,
        Rec12* __restrict__ rec,
        float* __restrict__ out) {
    __shared__ int h[NBUCK];
    __shared__ int base[NBUCK];
    int tid = threadIdx.x;
    int f = blockIdx.x * blockDim.x + tid;

    for (int g = f; g < NUM_NODES; g += FILL_THREADS) out[g] = 0.f;

    for (int j = tid; j < NBUCK; j += 1024) h[j] = 0;
    __syncthreads();

    bool valid = (f < NUM_FLOPS);
    int b1 = 0, b2 = -1, r1 = 0, r2 = 0, keby = 0;
    float cx = 0.f, cy = 0.f;
    if (valid) {
        int i = fi[f];
        cx = pos[i] + 0.5f * nsx[i];
        cy = pos[NUM_NODES + i] + 0.5f * nsy[i];
        int bx0 = (int)floorf(cx); bx0 = bx0 < 0 ? 0 : (bx0 > NBX - 1 ? NBX - 1 : bx0);
        int by0 = (int)floorf(cy); by0 = by0 < 0 ? 0 : (by0 > NBY - 1 ? NBY - 1 : by0);
        int2 cc = ((const int2*)cs)[f];
        keby = (by0 << 6) | (cc.x * NCE + cc.y);
        int yb = by0 / YB_ROWS;
        int rlo = by0 - yb * YB_ROWS;
        b1 = yb * NBX + bx0;
        r1 = atomicAdd(&h[b1], 1);
        if (rlo <= 1 && yb > 0)                       b2 = b1 - NBX;
        else if (rlo >= YB_ROWS - 2 && yb < NYB - 1)  b2 = b1 + NBX;
        if (b2 >= 0) r2 = atomicAdd(&h[b2], 1);
    }
    __syncthreads();
    for (int j = tid; j < NBUCK; j += 1024)
        base[j] = h[j] ? atomicAdd(&cnt[j], h[j]) : 0;
    __syncthreads();
    if (valid) {
        Rec12 v; v.cx = cx; v.cy = cy; v.keby = keby;
        int s1 = base[b1] + r1;
        if (s1 < CAPB) rec[(size_t)b1 * CAPB + s1] = v;
        if (b2 >= 0) {
            int s2 = base[b2] + r2;
            if (s2 < CAPB) rec[(size_t)b2 * CAPB + s2] = v;
        }
    }
}

__global__ void __launch_bounds__(512)
ff_main(const int* __restrict__ cnt,
        const Rec12* __restrict__ rec,
        float* __restrict__ scale) {
    __shared__ __align__(16) float acc[YB_ROWS * W * KSTRIDE];
    int tid = threadIdx.x;
    int c0 = blockIdx.x * W;
    int yb = blockIdx.y;
    int y0 = yb * YB_ROWS;

    for (int j = tid; j < YB_ROWS * W * KSTRIDE; j += 512) acc[j] = 0.f;
    __syncthreads();

    int c_lo = c0 - 2 < 0 ? 0 : c0 - 2;
    int c_hi = c0 + W + 1 > NBX - 1 ? NBX - 1 : c0 + W + 1;
    int nb = c_hi - c_lo + 1;
    int start[9];
    start[0] = 0;
#pragma unroll
    for (int k = 0; k < 8; ++k) {
        int n = 0;
        if (k < nb) { n = cnt[yb * NBX + c_lo + k]; n = n < CAPB ? n : CAPB; }
        start[k + 1] = start[k] + n;
    }
    int tot = start[8];
    const Rec12* bb = rec + (size_t)(yb * NBX + c_lo) * CAPB;

    int idx = tid;
    Rec12 v = {}; int kc = 0;
    if (idx < tot) {
        int k = 0, off = idx;
#pragma unroll
        for (int t = 1; t < 8; ++t) { bool g = idx >= start[t]; k = g ? t : k; off = g ? idx - start[t] : off; }
        v = bb[(size_t)k * CAPB + off];
        kc = k;
    }
    while (idx < tot) {
        int nidx = idx + 512;
        Rec12 vn = {}; int kn = 0;
        if (nidx < tot) {
            int k = 0, off = nidx;
#pragma unroll
            for (int t = 1; t < 8; ++t) { bool g = nidx >= start[t]; k = g ? t : k; off = g ? nidx - start[t] : off; }
            vn = bb[(size_t)k * CAPB + off];
            kn = k;
        }
        float cx = v.cx, cy = v.cy;
        int ke  = v.keby & 63;
        int by0 = v.keby >> 6;
        int bx0 = c_lo + kc;
        float ex[W + 1], ey[6];
#pragma unroll
        for (int i = 0; i <= W; ++i)
            ex[i] = fast_erf(((float)(c0 + i) - cx) * S_INVSQRT2);
#pragma unroll
        for (int j = 0; j < 6; ++j)
            ey[j] = fast_erf(((float)(by0 - 2 + j) - cy) * S_INVSQRT2);
        float dyq[5];
#pragma unroll
        for (int j = 0; j < 5; ++j) dyq[j] = ey[j + 1] - ey[j];
        int r0 = by0 - 2 - y0;
#pragma unroll
        for (int i = 0; i < W; ++i) {
            int col = c0 + i;
            if (col >= bx0 - 2 && col <= bx0 + 2) {
                float dxq = 0.25f * (ex[i + 1] - ex[i]);
                int cb = i * KSTRIDE + ke;
#pragma unroll
                for (int j = 0; j < 5; ++j) {
                    int rl = r0 + j;
                    if ((unsigned)rl < YB_ROWS)
                        lds_fadd(&acc[rl * (W * KSTRIDE) + cb], dxq * dyq[j]);
                }
            }
        }
        v = vn; kc = kn; idx = nidx;
    }
    __syncthreads();

    if (tid < YB_ROWS * W) {
        const float4* p = (const float4*)(acc + tid * KSTRIDE);
        float tot2 = 0.f, halves = 0.f;
#pragma unroll
        for (int ck = 0; ck < NCK; ++ck) {
            float q = 0.f;
#pragma unroll
            for (int h2 = 0; h2 < 2; ++h2) {
                float4 d = p[ck * 2 + h2];
                tot2 += d.x + d.y + d.z + d.w;
                q += ceilf(d.x * 0.25f) + ceilf(d.y * 0.25f) +
                     ceilf(d.z * 0.25f) + ceilf(d.w * 0.25f);
            }
            halves += ceilf(0.5f * q);
        }
        float slices = ceilf(0.5f * halves);
        int rl = tid >> 2, cl = tid & 3;
        scale[(c0 + cl) * NBY + y0 + rl] = (tot2 > 0.f) ? (slices / fmaxf(tot2, 1e-12f)) : 0.f;
    }
}

// ---------------- one-shot ablation probes ----------------
// Identical loop structure / control flow / active-lane masks to ff_main.
// MODE 0: no DS op (asm sink)          -> loop+erf+load floor
// MODE 1: ds_add_f32, conflict-free    -> per-lane atomic throughput, no collisions
// MODE 2: plain ds_write, real addrs   -> random-addr DS traffic, no RMW
template<int MODE>
__global__ void __launch_bounds__(512)
ff_probe(const int* __restrict__ cnt, const Rec12* __restrict__ rec) {
    if (g_probe_armed) return;
    __shared__ __align__(16) float acc[YB_ROWS * W * KSTRIDE];
    int tid = threadIdx.x;
    int c0 = blockIdx.x * W;
    int yb = blockIdx.y;
    int y0 = yb * YB_ROWS;
    for (int j = tid; j < YB_ROWS * W * KSTRIDE; j += 512) acc[j] = 0.f;
    __syncthreads();

    int c_lo = c0 - 2 < 0 ? 0 : c0 - 2;
    int c_hi = c0 + W + 1 > NBX - 1 ? NBX - 1 : c0 + W + 1;
    int nb = c_hi - c_lo + 1;
    int start[9];
    start[0] = 0;
#pragma unroll
    for (int k = 0; k < 8; ++k) {
        int n = 0;
        if (k < nb) { n = cnt[yb * NBX + c_lo + k]; n = n < CAPB ? n : CAPB; }
        start[k + 1] = start[k] + n;
    }
    int tot = start[8];
    const Rec12* bb = rec + (size_t)(yb * NBX + c_lo) * CAPB;

    for (int rep = 0; rep < PROBE_REPS; ++rep) {
        int idx = tid;
        Rec12 v = {}; int kc = 0;
        if (idx < tot) {
            int k = 0, off = idx;
#pragma unroll
            for (int t = 1; t < 8; ++t) { bool g = idx >= start[t]; k = g ? t : k; off = g ? idx - start[t] : off; }
            v = bb[(size_t)k * CAPB + off];
            kc = k;
        }
        while (idx < tot) {
            int nidx = idx + 512;
            Rec12 vn = {}; int kn = 0;
            if (nidx < tot) {
                int k = 0, off = nidx;
#pragma unroll
                for (int t = 1; t < 8; ++t) { bool g = nidx >= start[t]; k = g ? t : k; off = g ? nidx - start[t] : off; }
                vn = bb[(size_t)k * CAPB + off];
                kn = k;
            }
            float cx = v.cx, cy = v.cy;
            int ke  = v.keby & 63;
            int by0 = v.keby >> 6;
            int bx0 = c_lo + kc;
            float ex[W + 1], ey[6];
#pragma unroll
            for (int i = 0; i <= W; ++i)
                ex[i] = fast_erf(((float)(c0 + i) - cx) * S_INVSQRT2);
#pragma unroll
            for (int j = 0; j < 6; ++j)
                ey[j] = fast_erf(((float)(by0 - 2 + j) - cy) * S_INVSQRT2);
            float dyq[5];
#pragma unroll
            for (int j = 0; j < 5; ++j) dyq[j] = ey[j + 1] - ey[j];
            int r0 = by0 - 2 - y0;
#pragma unroll
            for (int i = 0; i < W; ++i) {
                int col = c0 + i;
                if (col >= bx0 - 2 && col <= bx0 + 2) {
                    float dxq = 0.25f * (ex[i + 1] - ex[i]);
                    int cb = i * KSTRIDE + ke;
#pragma unroll
                    for (int j = 0; j < 5; ++j) {
                        int rl = r0 + j;
                        if ((unsigned)rl < YB_ROWS) {
                            float val = dxq * dyq[j];
                            int addr = rl * (W * KSTRIDE) + cb;
                            if (MODE == 0) {
                                asm volatile("" :: "v"(val), "v"(addr));
                            } else if (MODE == 1) {
                                unsafeAtomicAdd(&acc[(tid & 63) * 25 + (i * 5 + j)], val);
                            } else {
                                acc[addr] = val;
                            }
                        }
                    }
                }
            }
            v = vn; kc = kn; idx = nidx;
        }
    }
    __syncthreads();
    asm volatile("" :: "v"(acc[tid]));   // keep LDS state live
}

__global__ void ff_arm() { g_probe_armed = 1; }

__global__ void ff_gather(const float* __restrict__ pos,
                          const float* __restrict__ nsx,
                          const float* __restrict__ nsy,
                          const int* __restrict__ fi,
                          const float* __restrict__ scale,
                          float* __restrict__ out) {
    int f = blockIdx.x * blockDim.x + threadIdx.x;
    if (f >= NUM_FLOPS) return;
    int i = fi[f];
    float cx = pos[i] + 0.5f * nsx[i];
    float cy = pos[NUM_NODES + i] + 0.5f * nsy[i];
    int bx0 = (int)floorf(cx); bx0 = bx0 < 0 ? 0 : (bx0 > NBX - 1 ? NBX - 1 : bx0);
    int by0 = (int)floorf(cy); by0 = by0 < 0 ? 0 : (by0 > NBY - 1 ? NBY - 1 : by0);
    out[i] = scale[bx0 * NBY + by0];
}

extern "C" void kernel_launch(void* const* d_in, const int* in_sizes, int n_in,
                              void* d_out, int out_size, void* d_ws, size_t ws_size,
                              hipStream_t stream) {
    const float* pos = (const float*)d_in[0];
    const float* nsx = (const float*)d_in[1];
    const float* nsy = (const float*)d_in[2];
    const int*   fi  = (const int*)d_in[3];
    const int*   cs  = (const int*)d_in[4];
    float* out = (float*)d_out;

    float* scale = (float*)d_ws;
    int*   cnt   = (int*)(scale + NBINS);
    Rec12* rec   = (Rec12*)(scale + NBINS + NBUCK);

    hipMemsetAsync(cnt, 0, NBUCK * sizeof(int), stream);

    ff_fill<<<784, 1024, 0, stream>>>(pos, nsx, nsy, fi, cs, cnt, rec, out);
    ff_main<<<dim3(NBX / W, NYB), 512, 0, stream>>>(cnt, rec, scale);
    ff_gather<<<(NUM_FLOPS + 255) / 256, 256, 0, stream>>>(pos, nsx, nsy, fi, scale, out);

    // one-shot ablation probes (heavy only on first iteration per process)
    ff_probe<0><<<dim3(NBX / W, NYB), 512, 0, stream>>>(cnt, rec);
    ff_probe<1><<<dim3(NBX / W, NYB), 512, 0, stream>>>(cnt, rec);
    ff_probe<2><<<dim3(NBX / W, NYB), 512, 0, stream>>>(cnt, rec);
    ff_arm<<<1, 1, 0, stream>>>();
}

// Round 7
// 188.120 us; speedup vs baseline: 5.6029x; 1.2714x over previous
//
#include <hip/hip_runtime.h>
#include <math.h>

#define NUM_NODES 2000000
#define NUM_FLOPS 800000
#define NBX 168
#define NBY 480
#define NCK 8
#define NCE 8
#define NBINS (NBX * NBY)          // 80,640
#define YB_ROWS 10                 // y-bucket / tile granularity
#define NYB 48                     // y-buckets per column
#define NBUCK (NYB * NBX)          // 8,064 buckets
#define CAPB 210                   // mean 139 (incl. halo dup), +6 sigma
#define W 4                        // columns owned per ff_main block
#define TILE_F (YB_ROWS * W * 64)  // 2,560 floats per wave-private tile (10 KB)
#define S_INVSQRT2 0.7071067811865476f
#define FILL_THREADS (784 * 1024)

// -------- workspace layout --------
// scale : float [NBINS]               (322.6 KB)
// cnt   : int   [NBUCK]               (32.3 KB)
// rec   : Rec12 [NBUCK * CAPB]        (20.32 MB)   total 20.68 MB < 20.97 MB cap

struct Rec12 { float cx, cy; int keby; };   // keby = (by0 << 6) | ke

// Branch-free erf, Abramowitz-Stegun 7.1.26 (max abs err 1.5e-7).
__device__ __forceinline__ float fast_erf(float x) {
    float ax = fabsf(x);
    float t = __builtin_amdgcn_rcpf(fmaf(0.3275911f, ax, 1.0f));
    float p = t * fmaf(t, fmaf(t, fmaf(t, fmaf(t, 1.061405429f, -1.453152027f),
                                       1.421413741f), -0.284496736f), 0.254829592f);
    float r = fmaf(-p, __expf(-ax * ax), 1.0f);
    return copysignf(r, x);
}

__global__ void __launch_bounds__(1024)
ff_fill(const float* __restrict__ pos,
        const float* __restrict__ nsx,
        const float* __restrict__ nsy,
        const int* __restrict__ fi,
        const int* __restrict__ cs,
        int* __restrict__ cnt,
        Rec12* __restrict__ rec,
        float* __restrict__ out) {
    __shared__ int h[NBUCK];
    __shared__ int base[NBUCK];
    int tid = threadIdx.x;
    int f = blockIdx.x * blockDim.x + tid;

    for (int g = f; g < NUM_NODES; g += FILL_THREADS) out[g] = 0.f;

    for (int j = tid; j < NBUCK; j += 1024) h[j] = 0;
    __syncthreads();

    bool valid = (f < NUM_FLOPS);
    int b1 = 0, b2 = -1, r1 = 0, r2 = 0, keby = 0;
    float cx = 0.f, cy = 0.f;
    if (valid) {
        int i = fi[f];
        cx = pos[i] + 0.5f * nsx[i];
        cy = pos[NUM_NODES + i] + 0.5f * nsy[i];
        int bx0 = (int)floorf(cx); bx0 = bx0 < 0 ? 0 : (bx0 > NBX - 1 ? NBX - 1 : bx0);
        int by0 = (int)floorf(cy); by0 = by0 < 0 ? 0 : (by0 > NBY - 1 ? NBY - 1 : by0);
        int2 cc = ((const int2*)cs)[f];
        keby = (by0 << 6) | (cc.x * NCE + cc.y);
        int yb = by0 / YB_ROWS;
        int rlo = by0 - yb * YB_ROWS;
        b1 = yb * NBX + bx0;
        r1 = atomicAdd(&h[b1], 1);
        if (rlo <= 1 && yb > 0)                       b2 = b1 - NBX;   // halo up
        else if (rlo >= YB_ROWS - 2 && yb < NYB - 1)  b2 = b1 + NBX;   // halo down
        if (b2 >= 0) r2 = atomicAdd(&h[b2], 1);
    }
    __syncthreads();
    for (int j = tid; j < NBUCK; j += 1024)
        base[j] = h[j] ? atomicAdd(&cnt[j], h[j]) : 0;
    __syncthreads();
    if (valid) {
        Rec12 v; v.cx = cx; v.cy = cy; v.keby = keby;
        int s1 = base[b1] + r1;
        if (s1 < CAPB) rec[(size_t)b1 * CAPB + s1] = v;
        if (b2 >= 0) {
            int s2 = base[b2] + r2;
            if (s2 < CAPB) rec[(size_t)b2 * CAPB + s2] = v;
        }
    }
}

// 4-wave block; wave w owns a PRIVATE 10x4x64 f32 tile -> no cross-wave races.
// Within-wave: lanes are grouped by ke (6-bit ballot); same-ke lanes serialize
// via rank-rounds. Within a round every active lane has a DISTINCT ke, and all
// tile addresses satisfy addr%64==ke -> all LDS accesses (across lanes AND
// cells) are provably distinct -> plain non-atomic += is race-free under ANY
// instruction order. One lgkmcnt(0)+compiler fence per round closes the only
// cross-round (same-ke) hazard. Also bank-conflict-free (<=2-way: ke, ke+32).
// (R6's (by0,ke)-keyed scheme lost adds: cross-blob same-address RMWs relied
// on per-wave DS FIFO under bank replay -> sparse-bin 1/16 flips, replay-
// unstable. This scheme needs no DS-ordering assumption at all.)
__global__ void __launch_bounds__(256, 4)
ff_main(const int* __restrict__ cnt,
        const Rec12* __restrict__ rec,
        float* __restrict__ scale) {
    __shared__ __align__(16) float sh[4 * TILE_F];   // 40,960 B -> 4 blocks/CU
    int tid = threadIdx.x;
    int wv = tid >> 6, lane = tid & 63;
    float* wtile = sh + wv * TILE_F;
    int c0 = blockIdx.x * W;
    int yb = blockIdx.y;
    int y0 = yb * YB_ROWS;

    for (int j = tid; j < TILE_F; j += 256)          // 4*TILE_F floats = TILE_F float4s
        ((float4*)sh)[j] = make_float4(0.f, 0.f, 0.f, 0.f);
    __syncthreads();

    int c_lo = c0 - 2 < 0 ? 0 : c0 - 2;
    int c_hi = c0 + W + 1 > NBX - 1 ? NBX - 1 : c0 + W + 1;
    int nb = c_hi - c_lo + 1;                        // 6..8
    int start[9];
    start[0] = 0;
#pragma unroll
    for (int k = 0; k < 8; ++k) {
        int n = 0;
        if (k < nb) { n = cnt[yb * NBX + c_lo + k]; n = n < CAPB ? n : CAPB; }
        start[k + 1] = start[k] + n;
    }
    int tot = start[8];
    const Rec12* bb = rec + (size_t)(yb * NBX + c_lo) * CAPB;

    for (int idx = tid; idx < tot; idx += 256) {
        int k = 0, off = idx;
#pragma unroll
        for (int t = 1; t < 8; ++t) { bool g = idx >= start[t]; k = g ? t : k; off = g ? idx - start[t] : off; }
        Rec12 v = bb[(size_t)k * CAPB + off];
        float cx = v.cx, cy = v.cy;
        int ke  = v.keby & 63;
        int by0 = v.keby >> 6;
        int bx0 = c_lo + k;                          // bucket column == record's bx0
        float ex[W + 1], ey[6];
#pragma unroll
        for (int i = 0; i <= W; ++i)                 // W+1 independent x-edge erfs
            ex[i] = fast_erf(((float)(c0 + i) - cx) * S_INVSQRT2);
#pragma unroll
        for (int j = 0; j < 6; ++j)                  // 6 independent y-edge erfs
            ey[j] = fast_erf(((float)(by0 - 2 + j) - cy) * S_INVSQRT2);
        float dyq[5];
#pragma unroll
        for (int j = 0; j < 5; ++j) dyq[j] = ey[j + 1] - ey[j];
        float dxq[W];
        int cmask = 0;
#pragma unroll
        for (int i = 0; i < W; ++i) {
            int col = c0 + i;
            dxq[i] = 0.25f * (ex[i + 1] - ex[i]);
            cmask |= (col >= bx0 - 2 && col <= bx0 + 2) ? (1 << i) : 0;
        }
        int r0 = by0 - 2 - y0;

        // group lanes by ke; ranks are consecutive 0..groupsize-1 per group
        unsigned long long peers = __ballot(1);
#pragma unroll
        for (int b = 0; b < 6; ++b) {
            unsigned long long bl = __ballot((ke >> b) & 1);
            peers &= ((ke >> b) & 1) ? bl : ~bl;
        }
        int rank = (int)__popcll(peers & ((1ull << lane) - 1ull));

        for (int r = 0;; ++r) {                      // rank-rounds
            if (!__ballot(rank == r)) break;
            if (rank == r) {
#pragma unroll
                for (int i = 0; i < W; ++i) {
                    if (cmask & (1 << i)) {
#pragma unroll
                        for (int j = 0; j < 5; ++j) {
                            int rl = r0 + j;
                            if ((unsigned)rl < YB_ROWS)
                                wtile[rl * (W * 64) + i * 64 + ke] += dxq[i] * dyq[j];
                        }
                    }
                }
            }
            // round boundary: drain LDS ops; memory clobber stops compiler
            // from moving next round's reads above this point
            asm volatile("s_waitcnt lgkmcnt(0)" ::: "memory");
        }
    }
    __syncthreads();

    // fused 4-way tile merge + quantization reduce: one thread per (row,col)
    if (tid < YB_ROWS * W) {
        int rl = tid >> 2, cl = tid & 3;
        int off = rl * (W * 64) + cl * 64;
        float tot2 = 0.f, halves = 0.f;
#pragma unroll
        for (int ck = 0; ck < NCK; ++ck) {
            float q = 0.f;
#pragma unroll
            for (int h2 = 0; h2 < 2; ++h2) {
                float4 d = make_float4(0.f, 0.f, 0.f, 0.f);
#pragma unroll
                for (int w2 = 0; w2 < 4; ++w2) {
                    float4 e = *(const float4*)(sh + w2 * TILE_F + off + ck * 8 + h2 * 4);
                    d.x += e.x; d.y += e.y; d.z += e.z; d.w += e.w;
                }
                tot2 += d.x + d.y + d.z + d.w;
                q += ceilf(d.x * 0.25f) + ceilf(d.y * 0.25f) +
                     ceilf(d.z * 0.25f) + ceilf(d.w * 0.25f);
            }
            halves += ceilf(0.5f * q);
        }
        float slices = ceilf(0.5f * halves);
        scale[(c0 + cl) * NBY + y0 + rl] = (tot2 > 0.f) ? (slices / fmaxf(tot2, 1e-12f)) : 0.f;
    }
}

__global__ void ff_gather(const float* __restrict__ pos,
                          const float* __restrict__ nsx,
                          const float* __restrict__ nsy,
                          const int* __restrict__ fi,
                          const float* __restrict__ scale,
                          float* __restrict__ out) {
    int f = blockIdx.x * blockDim.x + threadIdx.x;
    if (f >= NUM_FLOPS) return;
    int i = fi[f];
    float cx = pos[i] + 0.5f * nsx[i];
    float cy = pos[NUM_NODES + i] + 0.5f * nsy[i];
    int bx0 = (int)floorf(cx); bx0 = bx0 < 0 ? 0 : (bx0 > NBX - 1 ? NBX - 1 : bx0);
    int by0 = (int)floorf(cy); by0 = by0 < 0 ? 0 : (by0 > NBY - 1 ? NBY - 1 : by0);
    out[i] = scale[bx0 * NBY + by0];
}

extern "C" void kernel_launch(void* const* d_in, const int* in_sizes, int n_in,
                              void* d_out, int out_size, void* d_ws, size_t ws_size,
                              hipStream_t stream) {
    const float* pos = (const float*)d_in[0];
    const float* nsx = (const float*)d_in[1];
    const float* nsy = (const float*)d_in[2];
    const int*   fi  = (const int*)d_in[3];
    const int*   cs  = (const int*)d_in[4];
    float* out = (float*)d_out;

    float* scale = (float*)d_ws;
    int*   cnt   = (int*)(scale + NBINS);
    Rec12* rec   = (Rec12*)(scale + NBINS + NBUCK);

    hipMemsetAsync(cnt, 0, NBUCK * sizeof(int), stream);

    ff_fill<<<784, 1024, 0, stream>>>(pos, nsx, nsy, fi, cs, cnt, rec, out);
    ff_main<<<dim3(NBX / W, NYB), 256, 0, stream>>>(cnt, rec, scale);
    ff_gather<<<(NUM_FLOPS + 255) / 256, 256, 0, stream>>>(pos, nsx, nsy, fi, scale, out);
}

// Round 8
// 187.716 us; speedup vs baseline: 5.6149x; 1.0022x over previous
//
#include <hip/hip_runtime.h>
#include <math.h>

#define NUM_NODES 2000000
#define NUM_FLOPS 800000
#define NBX 168
#define NBY 480
#define NCK 8
#define NCE 8
#define NBINS (NBX * NBY)          // 80,640
#define YB_ROWS 10                 // y-bucket / tile granularity
#define NYB 48                     // y-buckets per column
#define NBUCK (NYB * NBX)          // 8,064 buckets
#define CAPB 210                   // mean 139 (incl. halo dup), +6 sigma
#define W 2                        // columns owned per ff_main block
#define TROWS (YB_ROWS + 8)        // padded tile rows: r0 in [-4,9] -> rows 0..17
#define TILE_F (TROWS * W * 64)    // 2,304 floats per wave-private tile (9,216 B)
#define S_INVSQRT2 0.7071067811865476f
#define FILL_THREADS (784 * 1024)

// -------- workspace layout --------
// scale : float [NBINS]               (322.6 KB)
// cnt   : int   [NBUCK]               (32.3 KB)
// rec   : Rec12 [NBUCK * CAPB]        (20.32 MB)   total 20.68 MB < 20.97 MB cap

struct Rec12 { float cx, cy; int keby; };   // keby = (by0 << 6) | ke

// Branch-free erf, Abramowitz-Stegun 7.1.26 (max abs err 1.5e-7).
__device__ __forceinline__ float fast_erf(float x) {
    float ax = fabsf(x);
    float t = __builtin_amdgcn_rcpf(fmaf(0.3275911f, ax, 1.0f));
    float p = t * fmaf(t, fmaf(t, fmaf(t, fmaf(t, 1.061405429f, -1.453152027f),
                                       1.421413741f), -0.284496736f), 0.254829592f);
    float r = fmaf(-p, __expf(-ax * ax), 1.0f);
    return copysignf(r, x);
}

__global__ void __launch_bounds__(1024)
ff_fill(const float* __restrict__ pos,
        const float* __restrict__ nsx,
        const float* __restrict__ nsy,
        const int* __restrict__ fi,
        const int* __restrict__ cs,
        int* __restrict__ cnt,
        Rec12* __restrict__ rec,
        float* __restrict__ out) {
    __shared__ int h[NBUCK];
    __shared__ int base[NBUCK];
    int tid = threadIdx.x;
    int f = blockIdx.x * blockDim.x + tid;

    for (int g = f; g < NUM_NODES; g += FILL_THREADS) out[g] = 0.f;

    for (int j = tid; j < NBUCK; j += 1024) h[j] = 0;
    __syncthreads();

    bool valid = (f < NUM_FLOPS);
    int b1 = 0, b2 = -1, r1 = 0, r2 = 0, keby = 0;
    float cx = 0.f, cy = 0.f;
    if (valid) {
        int i = fi[f];
        cx = pos[i] + 0.5f * nsx[i];
        cy = pos[NUM_NODES + i] + 0.5f * nsy[i];
        int bx0 = (int)floorf(cx); bx0 = bx0 < 0 ? 0 : (bx0 > NBX - 1 ? NBX - 1 : bx0);
        int by0 = (int)floorf(cy); by0 = by0 < 0 ? 0 : (by0 > NBY - 1 ? NBY - 1 : by0);
        int2 cc = ((const int2*)cs)[f];
        keby = (by0 << 6) | (cc.x * NCE + cc.y);
        int yb = by0 / YB_ROWS;
        int rlo = by0 - yb * YB_ROWS;
        b1 = yb * NBX + bx0;
        r1 = atomicAdd(&h[b1], 1);
        if (rlo <= 1 && yb > 0)                       b2 = b1 - NBX;   // halo up
        else if (rlo >= YB_ROWS - 2 && yb < NYB - 1)  b2 = b1 + NBX;   // halo down
        if (b2 >= 0) r2 = atomicAdd(&h[b2], 1);
    }
    __syncthreads();
    for (int j = tid; j < NBUCK; j += 1024)
        base[j] = h[j] ? atomicAdd(&cnt[j], h[j]) : 0;
    __syncthreads();
    if (valid) {
        Rec12 v; v.cx = cx; v.cy = cy; v.keby = keby;
        int s1 = base[b1] + r1;
        if (s1 < CAPB) rec[(size_t)b1 * CAPB + s1] = v;
        if (b2 >= 0) {
            int s2 = base[b2] + r2;
            if (s2 < CAPB) rec[(size_t)b2 * CAPB + s2] = v;
        }
    }
}

// 4-wave block; wave owns a PRIVATE padded tile: 18 rows x 2 cols x 64 ke
// (9,216 B) -> 36,864 B/block -> 4 blocks/CU. BRANCHLESS accumulation: all
// 5 y-rows land unconditionally (rows rr0..rr0+4 in [0,17] by fill
// construction; pad rows discarded at reduce -- their contributions are
// owned by neighbor tiles via the halo-dup records). x-window applied as a
// multiplicative 0/1 mask (+0.0f adds are value-neutral). This removes all
// per-cell branches and lets the 5 reads + 5 writes per col batch/merge.
// ke-rank-rounds (R7-proven): within a round all addresses distinct mod 64
// -> any order safe; cross-round closed by lgkmcnt(0)+clobber fence.
__global__ void __launch_bounds__(256, 4)
ff_main(const int* __restrict__ cnt,
        const Rec12* __restrict__ rec,
        float* __restrict__ scale) {
    __shared__ __align__(16) float sh[4 * TILE_F];   // 36,864 B
    int tid = threadIdx.x;
    int wv = tid >> 6, lane = tid & 63;
    float* wtile = sh + wv * TILE_F;
    int c0 = blockIdx.x * W;
    int yb = blockIdx.y;
    int y0 = yb * YB_ROWS;

    for (int j = tid; j < TILE_F; j += 256)          // 4*TILE_F floats = TILE_F float4
        ((float4*)sh)[j] = make_float4(0.f, 0.f, 0.f, 0.f);
    __syncthreads();

    int c_lo = c0 - 2 < 0 ? 0 : c0 - 2;
    int c_hi = c0 + W + 1 > NBX - 1 ? NBX - 1 : c0 + W + 1;
    int nb = c_hi - c_lo + 1;                        // 4..6
    int start[7];
    start[0] = 0;
#pragma unroll
    for (int k = 0; k < 6; ++k) {
        int n = 0;
        if (k < nb) { n = cnt[yb * NBX + c_lo + k]; n = n < CAPB ? n : CAPB; }
        start[k + 1] = start[k] + n;
    }
    int tot = start[6];
    const Rec12* bb = rec + (size_t)(yb * NBX + c_lo) * CAPB;

    for (int idx = tid; idx < tot; idx += 256) {
        int k = 0, off = idx;
#pragma unroll
        for (int t = 1; t < 6; ++t) { bool g = idx >= start[t]; k = g ? t : k; off = g ? idx - start[t] : off; }
        Rec12 v = bb[(size_t)k * CAPB + off];
        float cx = v.cx, cy = v.cy;
        int ke  = v.keby & 63;
        int by0 = v.keby >> 6;
        int bx0 = c_lo + k;                          // bucket column == record's bx0
        float ex[W + 1], ey[6];
#pragma unroll
        for (int i = 0; i <= W; ++i)
            ex[i] = fast_erf(((float)(c0 + i) - cx) * S_INVSQRT2);
#pragma unroll
        for (int j = 0; j < 6; ++j)
            ey[j] = fast_erf(((float)(by0 - 2 + j) - cy) * S_INVSQRT2);
        float dyq[5];
#pragma unroll
        for (int j = 0; j < 5; ++j) dyq[j] = ey[j + 1] - ey[j];
        float dxq[W];
#pragma unroll
        for (int i = 0; i < W; ++i) {
            int col = c0 + i;
            float m = (col >= bx0 - 2 && col <= bx0 + 2) ? 1.f : 0.f;   // x-window
            dxq[i] = 0.25f * (ex[i + 1] - ex[i]) * m;
        }
        int rr0 = by0 - y0 + 2;                      // in [0,13]; rows rr0..rr0+4 in [0,17]

        // group lanes by ke; ranks consecutive within group
        unsigned long long peers = __ballot(1);
#pragma unroll
        for (int b = 0; b < 6; ++b) {
            unsigned long long bl = __ballot((ke >> b) & 1);
            peers &= ((ke >> b) & 1) ? bl : ~bl;
        }
        int rank = (int)__popcll(peers & ((1ull << lane) - 1ull));

        for (int r = 0;; ++r) {                      // rank-rounds
            if (!__ballot(rank == r)) break;
            if (rank == r) {
                float* t0 = wtile + rr0 * (W * 64) + ke;
                // batched: 10 reads, 10 fmas, 10 writes (addresses distinct
                // across active lanes: all == ke mod 64; distinct within lane)
                float a0 = t0[0 * 128], a1 = t0[1 * 128], a2 = t0[2 * 128],
                      a3 = t0[3 * 128], a4 = t0[4 * 128];
                float b0 = t0[0 * 128 + 64], b1 = t0[1 * 128 + 64], b2 = t0[2 * 128 + 64],
                      b3 = t0[3 * 128 + 64], b4 = t0[4 * 128 + 64];
                a0 = fmaf(dxq[0], dyq[0], a0); b0 = fmaf(dxq[1], dyq[0], b0);
                a1 = fmaf(dxq[0], dyq[1], a1); b1 = fmaf(dxq[1], dyq[1], b1);
                a2 = fmaf(dxq[0], dyq[2], a2); b2 = fmaf(dxq[1], dyq[2], b2);
                a3 = fmaf(dxq[0], dyq[3], a3); b3 = fmaf(dxq[1], dyq[3], b3);
                a4 = fmaf(dxq[0], dyq[4], a4); b4 = fmaf(dxq[1], dyq[4], b4);
                t0[0 * 128] = a0; t0[1 * 128] = a1; t0[2 * 128] = a2;
                t0[3 * 128] = a3; t0[4 * 128] = a4;
                t0[0 * 128 + 64] = b0; t0[1 * 128 + 64] = b1; t0[2 * 128 + 64] = b2;
                t0[3 * 128 + 64] = b3; t0[4 * 128 + 64] = b4;
            }
            // round boundary: drain this round's LDS ops before next round's
            // (same-ke) lanes read the same addresses
            asm volatile("s_waitcnt lgkmcnt(0)" ::: "memory");
        }
    }
    __syncthreads();

    // fused 4-way tile merge + quantization reduce: one thread per (row,col);
    // valid rows are rr = 4..13 (pads 0..3 / 14..17 discarded)
    if (tid < YB_ROWS * W) {
        int rl = tid >> 1, cl = tid & 1;
        int off = (rl + 4) * (W * 64) + cl * 64;
        float tot2 = 0.f, halves = 0.f;
#pragma unroll
        for (int ck = 0; ck < NCK; ++ck) {
            float q = 0.f;
#pragma unroll
            for (int h2 = 0; h2 < 2; ++h2) {
                float4 d = make_float4(0.f, 0.f, 0.f, 0.f);
#pragma unroll
                for (int w2 = 0; w2 < 4; ++w2) {
                    float4 e = *(const float4*)(sh + w2 * TILE_F + off + ck * 8 + h2 * 4);
                    d.x += e.x; d.y += e.y; d.z += e.z; d.w += e.w;
                }
                tot2 += d.x + d.y + d.z + d.w;
                q += ceilf(d.x * 0.25f) + ceilf(d.y * 0.25f) +
                     ceilf(d.z * 0.25f) + ceilf(d.w * 0.25f);
            }
            halves += ceilf(0.5f * q);
        }
        float slices = ceilf(0.5f * halves);
        scale[(c0 + cl) * NBY + y0 + rl] = (tot2 > 0.f) ? (slices / fmaxf(tot2, 1e-12f)) : 0.f;
    }
}

__global__ void ff_gather(const float* __restrict__ pos,
                          const float* __restrict__ nsx,
                          const float* __restrict__ nsy,
                          const int* __restrict__ fi,
                          const float* __restrict__ scale,
                          float* __restrict__ out) {
    int f = blockIdx.x * blockDim.x + threadIdx.x;
    if (f >= NUM_FLOPS) return;
    int i = fi[f];
    float cx = pos[i] + 0.5f * nsx[i];
    float cy = pos[NUM_NODES + i] + 0.5f * nsy[i];
    int bx0 = (int)floorf(cx); bx0 = bx0 < 0 ? 0 : (bx0 > NBX - 1 ? NBX - 1 : bx0);
    int by0 = (int)floorf(cy); by0 = by0 < 0 ? 0 : (by0 > NBY - 1 ? NBY - 1 : by0);
    out[i] = scale[bx0 * NBY + by0];
}

extern "C" void kernel_launch(void* const* d_in, const int* in_sizes, int n_in,
                              void* d_out, int out_size, void* d_ws, size_t ws_size,
                              hipStream_t stream) {
    const float* pos = (const float*)d_in[0];
    const float* nsx = (const float*)d_in[1];
    const float* nsy = (const float*)d_in[2];
    const int*   fi  = (const int*)d_in[3];
    const int*   cs  = (const int*)d_in[4];
    float* out = (float*)d_out;

    float* scale = (float*)d_ws;
    int*   cnt   = (int*)(scale + NBINS);
    Rec12* rec   = (Rec12*)(scale + NBINS + NBUCK);

    hipMemsetAsync(cnt, 0, NBUCK * sizeof(int), stream);

    ff_fill<<<784, 1024, 0, stream>>>(pos, nsx, nsy, fi, cs, cnt, rec, out);
    ff_main<<<dim3(NBX / W, NYB), 256, 0, stream>>>(cnt, rec, scale);
    ff_gather<<<(NUM_FLOPS + 255) / 256, 256, 0, stream>>>(pos, nsx, nsy, fi, scale, out);
}

// Round 10
// 163.669 us; speedup vs baseline: 6.4399x; 1.1469x over previous
//
#include <hip/hip_runtime.h>
#include <math.h>

#define NUM_NODES 2000000
#define NUM_FLOPS 800000
#define NBX 168
#define NBY 480
#define NCK 8
#define NCE 8
#define NBINS (NBX * NBY)          // 80,640
#define YB_ROWS 10                 // y-bucket / tile granularity
#define NYB 48                     // y-buckets per column
// Column mass is NOT uniform: bx0 = floor(pos + 0.5*nsx) clipped -> col 167
// absorbs all cx>=167: P = (1+0.5*E[nsx])/168 ~= 1.275x mean -> E ~= 6,070.
// (R9 sized CAPC off the 4,762 mean and silently dropped ~800 col-167
// records -> absmax 0.45. Rule: capacity must cover the WORST column.)
#define CAPC 6720                  // per-column PRE-dup cap (worst col 6,070 +8 sigma)
#define CAPR 9600                  // per-column POST-dup slots (6,700 * 1.4 halo)
#define SORT_IT 7                  // ceil(CAPC/1024)
#define W 2                        // columns owned per ff_main block
#define TROWS (YB_ROWS + 8)        // padded tile rows
#define TILE_F (TROWS * W * 64)    // 2,304 floats per wave-private tile
#define S_INVSQRT2 0.7071067811865476f
#define P1_FLOPS 4096              // flops per pass-1 block
#define P1_BLOCKS 196              // ceil(800000/4096)

// -------- workspace layout --------
// scale  : float [NBINS]                (322.6 KB)
// colcnt : int   [NBX]                  (672 B)
// bstart : int   [NBX*NYB]              (32.3 KB)
// bcnt   : int   [NBX*NYB]              (32.3 KB)
// rec    : Rec12 [NBX * CAPR]           (19.35 MB)   total ~19.76 MB < 20.97 MB cap

struct Rec12 { float cx, cy; int keby; };   // keby = (bx0<<15) | (by0<<6) | ke

// Branch-free erf, Abramowitz-Stegun 7.1.26 (max abs err 1.5e-7).
__device__ __forceinline__ float fast_erf(float x) {
    float ax = fabsf(x);
    float t = __builtin_amdgcn_rcpf(fmaf(0.3275911f, ax, 1.0f));
    float p = t * fmaf(t, fmaf(t, fmaf(t, fmaf(t, 1.061405429f, -1.453152027f),
                                       1.421413741f), -0.284496736f), 0.254829592f);
    float r = fmaf(-p, __expf(-ax * ax), 1.0f);
    return copysignf(r, x);
}

// -------- pass 1: column-grouped coalesced scatter --------
// R8 counters: old fill wrote 63MB for 13.4MB payload (19% line utilization,
// 12B records on random lines) -> 64us @ ~1TB/s scatter ceiling. Here each
// block LDS-sorts 4096 records by column (168 bins) and writes runs of ~24
// consecutive records per column (~290B, ~80% utilization).
__global__ void __launch_bounds__(1024)
ff_fill(const float* __restrict__ pos,
        const float* __restrict__ nsx,
        const float* __restrict__ nsy,
        const int* __restrict__ fi,
        const int* __restrict__ cs,
        int* __restrict__ colcnt,
        Rec12* __restrict__ rec,
        float* __restrict__ out) {
    __shared__ int hist[NBX];
    __shared__ int ofs[NBX];
    __shared__ int gbase[NBX];
    __shared__ int sc[NBX];
    __shared__ int tot_s;
    __shared__ Rec12 staged[P1_FLOPS];        // 49.2 KB
    int tid = threadIdx.x;
    int f0 = blockIdx.x * P1_FLOPS;

    // fused: zero the output array
    for (int g = blockIdx.x * 1024 + tid; g < NUM_NODES; g += P1_BLOCKS * 1024)
        out[g] = 0.f;

    for (int j = tid; j < NBX; j += 1024) hist[j] = 0;
    __syncthreads();

    int colq[4], r1q[4], kebyq[4];
    float cxq[4], cyq[4];
    bool vq[4];
#pragma unroll
    for (int q = 0; q < 4; ++q) {
        int f = f0 + q * 1024 + tid;
        bool valid = f < NUM_FLOPS;
        vq[q] = valid; colq[q] = 0; r1q[q] = 0; kebyq[q] = 0; cxq[q] = 0.f; cyq[q] = 0.f;
        if (valid) {
            int i = fi[f];
            float cx = pos[i] + 0.5f * nsx[i];
            float cy = pos[NUM_NODES + i] + 0.5f * nsy[i];
            int bx0 = (int)floorf(cx); bx0 = bx0 < 0 ? 0 : (bx0 > NBX - 1 ? NBX - 1 : bx0);
            int by0 = (int)floorf(cy); by0 = by0 < 0 ? 0 : (by0 > NBY - 1 ? NBY - 1 : by0);
            int2 cc = ((const int2*)cs)[f];
            int ke = cc.x * NCE + cc.y;
            colq[q] = bx0; cxq[q] = cx; cyq[q] = cy;
            kebyq[q] = (bx0 << 15) | (by0 << 6) | ke;
            r1q[q] = atomicAdd(&hist[bx0], 1);
        }
    }
    __syncthreads();
    // exclusive scan of hist[168] (Hillis-Steele)
    if (tid < NBX) sc[tid] = hist[tid];
    __syncthreads();
    for (int d = 1; d < NBX; d <<= 1) {
        int v2 = 0;
        if (tid < NBX && tid >= d) v2 = sc[tid - d];
        __syncthreads();
        if (tid < NBX) sc[tid] += v2;
        __syncthreads();
    }
    if (tid < NBX) {
        ofs[tid] = sc[tid] - hist[tid];
        int nn = hist[tid];
        gbase[tid] = nn ? atomicAdd(&colcnt[tid], nn) : 0;   // one atomic per (block,col)
    }
    if (tid == 0) tot_s = sc[NBX - 1];
    __syncthreads();
#pragma unroll
    for (int q = 0; q < 4; ++q)
        if (vq[q]) {
            Rec12 v; v.cx = cxq[q]; v.cy = cyq[q]; v.keby = kebyq[q];
            staged[ofs[colq[q]] + r1q[q]] = v;
        }
    __syncthreads();
    // coalesced copy-out: consecutive t -> same column -> consecutive slots
    for (int t = tid; t < tot_s; t += 1024) {
        Rec12 v = staged[t];
        int c = (v.keby >> 15) & 255;
        int slot = gbase[c] + (t - ofs[c]);
        if (slot < CAPC) rec[(size_t)c * CAPR + slot] = v;
    }
}

// -------- pass 2: per-column yb-sort (+ halo dup) with exact offsets --------
// One block per column: stage column in LDS (~80.6 KB + 19.2 KB perm; gfx950
// allows >64KB static LDS, 128KB precedent), rank by yb (incl. halo dup) via
// LDS int atomics, write back FULLY COALESCED in-place; emit exact
// per-bucket (bstart,bcnt).
__global__ void __launch_bounds__(1024)
ff_sort(const int* __restrict__ colcnt,
        Rec12* __restrict__ rec,
        int* __restrict__ bstart,
        int* __restrict__ bcnt) {
    __shared__ Rec12 staged[CAPC];            // 80.6 KB
    __shared__ unsigned short perm[CAPR];     // 19.2 KB
    __shared__ int hist[NYB];
    __shared__ int ofs[NYB + 1];
    int c = blockIdx.x;
    int tid = threadIdx.x;
    int n = colcnt[c]; n = n < CAPC ? n : CAPC;
    Rec12* col = rec + (size_t)c * CAPR;
    for (int t = tid; t < n; t += 1024) staged[t] = col[t];
    if (tid < NYB) hist[tid] = 0;
    __syncthreads();

    int sP[SORT_IT], sH[SORT_IT], ybq[SORT_IT], ybhq[SORT_IT];   // regs, const-idx
#pragma unroll
    for (int it = 0; it < SORT_IT; ++it) {
        int t = it * 1024 + tid;
        sP[it] = 0; sH[it] = 0; ybq[it] = 0; ybhq[it] = -1;
        if (t < n) {
            int by0 = (staged[t].keby >> 6) & 511;
            int yb = by0 / YB_ROWS;
            int rlo = by0 - yb * YB_ROWS;
            ybq[it] = yb;
            sP[it] = atomicAdd(&hist[yb], 1);
            int ybh = (rlo <= 1 && yb > 0) ? yb - 1
                    : ((rlo >= YB_ROWS - 2 && yb < NYB - 1) ? yb + 1 : -1);
            ybhq[it] = ybh;
            if (ybh >= 0) sH[it] = atomicAdd(&hist[ybh], 1);
        }
    }
    __syncthreads();
    if (tid == 0) {
        int s = 0;
        for (int g = 0; g < NYB; ++g) { ofs[g] = s; s += hist[g]; }
        ofs[NYB] = s;
    }
    __syncthreads();
#pragma unroll
    for (int it = 0; it < SORT_IT; ++it) {
        int t = it * 1024 + tid;
        if (t < n) {
            int ip = ofs[ybq[it]] + sP[it];
            if (ip < CAPR) perm[ip] = (unsigned short)t;
            if (ybhq[it] >= 0) {
                int ih = ofs[ybhq[it]] + sH[it];
                if (ih < CAPR) perm[ih] = (unsigned short)t;
            }
        }
    }
    __syncthreads();
    int m = ofs[NYB]; m = m < CAPR ? m : CAPR;
    for (int t = tid; t < m; t += 1024) col[t] = staged[perm[t]];   // coalesced
    if (tid < NYB) {
        int s0 = ofs[tid];             s0 = s0 < CAPR ? s0 : CAPR;
        int e0 = ofs[tid] + hist[tid]; e0 = e0 < CAPR ? e0 : CAPR;
        bstart[c * NYB + tid] = c * CAPR + s0;
        bcnt[c * NYB + tid]   = e0 - s0;
    }
}

// -------- main: unchanged R8 core, bucket addressing via bstart/bcnt --------
__global__ void __launch_bounds__(256, 4)
ff_main(const int* __restrict__ bstart,
        const int* __restrict__ bcnt,
        const Rec12* __restrict__ rec,
        float* __restrict__ scale) {
    __shared__ __align__(16) float sh[4 * TILE_F];   // 36,864 B
    int tid = threadIdx.x;
    int wv = tid >> 6, lane = tid & 63;
    float* wtile = sh + wv * TILE_F;
    int c0 = blockIdx.x * W;
    int yb = blockIdx.y;
    int y0 = yb * YB_ROWS;

    for (int j = tid; j < TILE_F; j += 256)
        ((float4*)sh)[j] = make_float4(0.f, 0.f, 0.f, 0.f);
    __syncthreads();

    int c_lo = c0 - 2 < 0 ? 0 : c0 - 2;
    int c_hi = c0 + W + 1 > NBX - 1 ? NBX - 1 : c0 + W + 1;
    int nb = c_hi - c_lo + 1;                        // 4..6
    int start[7], sb6[6];
    start[0] = 0;
#pragma unroll
    for (int k = 0; k < 6; ++k) {
        int nrec = 0, sbv = 0;
        if (k < nb) {
            int b = (c_lo + k) * NYB + yb;
            nrec = bcnt[b]; sbv = bstart[b];
        }
        sb6[k] = sbv;
        start[k + 1] = start[k] + nrec;
    }
    int tot = start[6];

    for (int idx = tid; idx < tot; idx += 256) {
        int k = 0, off = idx, base = sb6[0];
#pragma unroll
        for (int t = 1; t < 6; ++t) {
            bool g = idx >= start[t];
            k = g ? t : k; off = g ? idx - start[t] : off; base = g ? sb6[t] : base;
        }
        Rec12 v = rec[(size_t)(base + off)];
        float cx = v.cx, cy = v.cy;
        int ke  = v.keby & 63;
        int by0 = (v.keby >> 6) & 511;
        int bx0 = c_lo + k;                          // bucket column == record's bx0
        float ex[W + 1], ey[6];
#pragma unroll
        for (int i = 0; i <= W; ++i)
            ex[i] = fast_erf(((float)(c0 + i) - cx) * S_INVSQRT2);
#pragma unroll
        for (int j = 0; j < 6; ++j)
            ey[j] = fast_erf(((float)(by0 - 2 + j) - cy) * S_INVSQRT2);
        float dyq[5];
#pragma unroll
        for (int j = 0; j < 5; ++j) dyq[j] = ey[j + 1] - ey[j];
        float dxq[W];
#pragma unroll
        for (int i = 0; i < W; ++i) {
            int col = c0 + i;
            float mm = (col >= bx0 - 2 && col <= bx0 + 2) ? 1.f : 0.f;
            dxq[i] = 0.25f * (ex[i + 1] - ex[i]) * mm;
        }
        int rr0 = by0 - y0 + 2;                      // in [0,13]

        unsigned long long peers = __ballot(1);
#pragma unroll
        for (int b = 0; b < 6; ++b) {
            unsigned long long bl = __ballot((ke >> b) & 1);
            peers &= ((ke >> b) & 1) ? bl : ~bl;
        }
        int rank = (int)__popcll(peers & ((1ull << lane) - 1ull));

        for (int r = 0;; ++r) {                      // ke-rank-rounds (R7-proven)
            if (!__ballot(rank == r)) break;
            if (rank == r) {
                float* t0 = wtile + rr0 * (W * 64) + ke;
                float a0 = t0[0 * 128], a1 = t0[1 * 128], a2 = t0[2 * 128],
                      a3 = t0[3 * 128], a4 = t0[4 * 128];
                float b0 = t0[0 * 128 + 64], b1 = t0[1 * 128 + 64], b2 = t0[2 * 128 + 64],
                      b3 = t0[3 * 128 + 64], b4 = t0[4 * 128 + 64];
                a0 = fmaf(dxq[0], dyq[0], a0); b0 = fmaf(dxq[1], dyq[0], b0);
                a1 = fmaf(dxq[0], dyq[1], a1); b1 = fmaf(dxq[1], dyq[1], b1);
                a2 = fmaf(dxq[0], dyq[2], a2); b2 = fmaf(dxq[1], dyq[2], b2);
                a3 = fmaf(dxq[0], dyq[3], a3); b3 = fmaf(dxq[1], dyq[3], b3);
                a4 = fmaf(dxq[0], dyq[4], a4); b4 = fmaf(dxq[1], dyq[4], b4);
                t0[0 * 128] = a0; t0[1 * 128] = a1; t0[2 * 128] = a2;
                t0[3 * 128] = a3; t0[4 * 128] = a4;
                t0[0 * 128 + 64] = b0; t0[1 * 128 + 64] = b1; t0[2 * 128 + 64] = b2;
                t0[3 * 128 + 64] = b3; t0[4 * 128 + 64] = b4;
            }
            asm volatile("s_waitcnt lgkmcnt(0)" ::: "memory");
        }
    }
    __syncthreads();

    if (tid < YB_ROWS * W) {
        int rl = tid >> 1, cl = tid & 1;
        int off = (rl + 4) * (W * 64) + cl * 64;
        float tot2 = 0.f, halves = 0.f;
#pragma unroll
        for (int ck = 0; ck < NCK; ++ck) {
            float q = 0.f;
#pragma unroll
            for (int h2 = 0; h2 < 2; ++h2) {
                float4 d = make_float4(0.f, 0.f, 0.f, 0.f);
#pragma unroll
                for (int w2 = 0; w2 < 4; ++w2) {
                    float4 e = *(const float4*)(sh + w2 * TILE_F + off + ck * 8 + h2 * 4);
                    d.x += e.x; d.y += e.y; d.z += e.z; d.w += e.w;
                }
                tot2 += d.x + d.y + d.z + d.w;
                q += ceilf(d.x * 0.25f) + ceilf(d.y * 0.25f) +
                     ceilf(d.z * 0.25f) + ceilf(d.w * 0.25f);
            }
            halves += ceilf(0.5f * q);
        }
        float slices = ceilf(0.5f * halves);
        scale[(c0 + cl) * NBY + y0 + rl] = (tot2 > 0.f) ? (slices / fmaxf(tot2, 1e-12f)) : 0.f;
    }
}

__global__ void ff_gather(const float* __restrict__ pos,
                          const float* __restrict__ nsx,
                          const float* __restrict__ nsy,
                          const int* __restrict__ fi,
                          const float* __restrict__ scale,
                          float* __restrict__ out) {
    int f = blockIdx.x * blockDim.x + threadIdx.x;
    if (f >= NUM_FLOPS) return;
    int i = fi[f];
    float cx = pos[i] + 0.5f * nsx[i];
    float cy = pos[NUM_NODES + i] + 0.5f * nsy[i];
    int bx0 = (int)floorf(cx); bx0 = bx0 < 0 ? 0 : (bx0 > NBX - 1 ? NBX - 1 : bx0);
    int by0 = (int)floorf(cy); by0 = by0 < 0 ? 0 : (by0 > NBY - 1 ? NBY - 1 : by0);
    out[i] = scale[bx0 * NBY + by0];
}

extern "C" void kernel_launch(void* const* d_in, const int* in_sizes, int n_in,
                              void* d_out, int out_size, void* d_ws, size_t ws_size,
                              hipStream_t stream) {
    const float* pos = (const float*)d_in[0];
    const float* nsx = (const float*)d_in[1];
    const float* nsy = (const float*)d_in[2];
    const int*   fi  = (const int*)d_in[3];
    const int*   cs  = (const int*)d_in[4];
    float* out = (float*)d_out;

    float* scale  = (float*)d_ws;
    int*   colcnt = (int*)(scale + NBINS);
    int*   bstart = colcnt + NBX;
    int*   bcnt   = bstart + NBX * NYB;
    Rec12* rec    = (Rec12*)(bcnt + NBX * NYB);

    hipMemsetAsync(colcnt, 0, NBX * sizeof(int), stream);

    ff_fill<<<P1_BLOCKS, 1024, 0, stream>>>(pos, nsx, nsy, fi, cs, colcnt, rec, out);
    ff_sort<<<NBX, 1024, 0, stream>>>(colcnt, rec, bstart, bcnt);
    ff_main<<<dim3(NBX / W, NYB), 256, 0, stream>>>(bstart, bcnt, rec, scale);
    ff_gather<<<(NUM_FLOPS + 255) / 256, 256, 0, stream>>>(pos, nsx, nsy, fi, scale, out);
}